// Round 1
// baseline (1832.978 us; speedup 1.0000x reference)
//
#include <hip/hip_runtime.h>
#include <cstdint>
#include <cstddef>

#define NB 64          // batch (queries)
#define DD 256         // feature dim
#define NKEYS 500000
#define TOPK 32
#define NW 2048        // number of streaming waves (1 wave = 1 block of 64)
#define NTILES ((NKEYS + 63) / 64)   // 7813
#define CPW 16         // candidates kept per (wave, query)

// ---- float <-> order-preserving u32 ----
__device__ __forceinline__ unsigned int f2sort(float f) {
  unsigned int u = __float_as_uint(f);
  return u ^ ((unsigned int)((int)u >> 31) | 0x80000000u);
}
__device__ __forceinline__ float sort2f(unsigned int u) {
  unsigned int b = (u & 0x80000000u) ? (u ^ 0x80000000u) : ~u;
  return __uint_as_float(b);
}

// ---- K1: q_proj = (query @ Wq^T + bq) / 16  -> qs [64][256] ----
__global__ __launch_bounds__(256) void qproj_kernel(
    const float* __restrict__ query, const float* __restrict__ Wq,
    const float* __restrict__ bq, float* __restrict__ qs) {
  const int b = blockIdx.x;      // query row
  const int j = threadIdx.x;     // output feature
  const float4* wr = (const float4*)(Wq + (size_t)j * DD);
  float acc = bq[j];
  for (int dq = 0; dq < DD / 4; ++dq) {
    float4 wv = wr[dq];
    float4 qv = *(const float4*)(query + b * DD + dq * 4);  // wave-uniform -> s_load
    acc = fmaf(qv.x, wv.x, acc);
    acc = fmaf(qv.y, wv.y, acc);
    acc = fmaf(qv.z, wv.z, acc);
    acc = fmaf(qv.w, wv.w, acc);
  }
  qs[b * DD + j] = acc * 0.0625f;  // fold 1/sqrt(256) into q
}

// ---- K2: stream keys, scores for all 64 queries, online softmax + top-CPW ----
__global__ __launch_bounds__(64) void score_topk_kernel(
    const float* __restrict__ keys, const float* __restrict__ qs,
    float* __restrict__ maxes, float* __restrict__ sums,
    unsigned long long* __restrict__ cands) {
  __shared__ float sc[64 * 65];       // score tile [query][key-lane], +1 pad
  const int lane = threadIdx.x;       // = key-in-tile for compute, = query for bookkeeping
  const int w = blockIdx.x;

  float m = -INFINITY, sum = 0.f;     // online softmax state (query = lane)
  int cnt = 0;
  unsigned long long gmin = 0ull;     // min of my candidate list (packed)
  int gpos = 0;
  unsigned long long* myc = cands + ((size_t)w * NB + lane) * CPW;

  for (int t = w; t < NTILES; t += NW) {
    const int key = t * 64 + lane;
    const bool valid = key < NKEYS;
    const float4* kr4 = (const float4*)(keys + (size_t)(valid ? key : 0) * DD);

    float acc[NB];
#pragma unroll
    for (int b = 0; b < NB; ++b) acc[b] = 0.f;

    float4 kv = kr4[0];
    for (int dq = 0; dq < DD / 4; ++dq) {
      const int dn = (dq + 1 < DD / 4) ? dq + 1 : dq;
      float4 nkv = kr4[dn];           // prefetch (branchless)
      const int d0 = dq * 4;
#pragma unroll
      for (int b = 0; b < NB; ++b) {
        float4 qv = *(const float4*)(qs + b * DD + d0);  // uniform -> s_load_dwordx4
        acc[b] = fmaf(qv.x, kv.x, acc[b]);
        acc[b] = fmaf(qv.y, kv.y, acc[b]);
        acc[b] = fmaf(qv.z, kv.z, acc[b]);
        acc[b] = fmaf(qv.w, kv.w, acc[b]);
      }
      kv = nkv;
    }

#pragma unroll
    for (int b = 0; b < NB; ++b)
      sc[b * 65 + lane] = valid ? acc[b] : -INFINITY;
    __syncthreads();

    // bookkeeping: lane owns query 'lane'
    const int base = t * 64;
    for (int k2 = 0; k2 < 64; ++k2) {
      float s = sc[lane * 65 + k2];
      if (s == -INFINITY) continue;
      if (s > m) { sum = sum * __expf(m - s) + 1.0f; m = s; }
      else       { sum += __expf(s - m); }

      unsigned long long pk =
          ((unsigned long long)f2sort(s) << 32) | (unsigned int)(~(base + k2));
      if (cnt < CPW) {
        myc[cnt++] = pk;
        if (cnt == CPW) {
          gmin = myc[0]; gpos = 0;
#pragma unroll
          for (int i = 1; i < CPW; ++i) {
            unsigned long long v = myc[i];
            if (v < gmin) { gmin = v; gpos = i; }
          }
        }
      } else if (pk > gmin) {
        myc[gpos] = pk;
        gmin = myc[0]; gpos = 0;
#pragma unroll
        for (int i = 1; i < CPW; ++i) {
          unsigned long long v = myc[i];
          if (v < gmin) { gmin = v; gpos = i; }
        }
      }
    }
    __syncthreads();
  }

  for (int i = cnt; i < CPW; ++i) myc[i] = 0ull;  // sentinel = -inf
  maxes[w * NB + lane] = m;
  sums[w * NB + lane] = sum;
}

// ---- K3: per query merge softmax stats + global top-32 ----
__global__ __launch_bounds__(256) void merge_kernel(
    const float* __restrict__ maxes, const float* __restrict__ sums,
    const unsigned long long* __restrict__ cands,
    int* __restrict__ sel_idx, float* __restrict__ sel_w) {
  const int b = blockIdx.x;
  const int tid = threadIdx.x;
  __shared__ float red_m[256], red_s[256];
  __shared__ unsigned long long pool[256 * 8];
  __shared__ unsigned long long red[256];
  __shared__ float bc_M, bc_S;

  // phase A: merge (max, sumexp)
  float M = -INFINITY, S = 0.f;
  for (int w = tid; w < NW; w += 256) {
    float mi = maxes[w * NB + b];
    float si = sums[w * NB + b];
    if (mi == -INFINITY) continue;
    if (mi > M) { S = S * __expf(M - mi) + si; M = mi; }
    else        { S += si * __expf(mi - M); }
  }
  red_m[tid] = M; red_s[tid] = S;
  __syncthreads();
  if (tid == 0) {
    float Mm = -INFINITY, Ss = 0.f;
    for (int i = 0; i < 256; ++i) {
      float mi = red_m[i], si = red_s[i];
      if (mi == -INFINITY) continue;
      if (mi > Mm) { Ss = Ss * __expf(Mm - mi) + si; Mm = mi; }
      else         { Ss += si * __expf(mi - Mm); }
    }
    bc_M = Mm; bc_S = Ss;
  }

  // phase B: per-thread local top-8 of its candidate slice
  unsigned long long* mine = pool + tid * 8;
#pragma unroll
  for (int i = 0; i < 8; ++i) mine[i] = 0ull;
  unsigned long long lmin = 0ull; int lpos = 0;
  for (int w = tid; w < NW; w += 256) {
    const unsigned long long* src = cands + ((size_t)w * NB + b) * CPW;
#pragma unroll
    for (int j = 0; j < CPW; ++j) {
      unsigned long long pk = src[j];
      if (pk > lmin) {
        mine[lpos] = pk;
        lmin = mine[0]; lpos = 0;
#pragma unroll
        for (int i = 1; i < 8; ++i) {
          if (mine[i] < lmin) { lmin = mine[i]; lpos = i; }
        }
      }
    }
  }
  __syncthreads();
  const float Mf = bc_M, Sf = bc_S;

  // phase C: 32 rounds of block-wide argmax over the 2048-entry pool
  for (int r = 0; r < TOPK; ++r) {
    unsigned long long best = 0ull;
    for (int i = tid; i < 2048; i += 256) {
      unsigned long long v = pool[i];
      if (v > best) best = v;
    }
    red[tid] = best;
    __syncthreads();
    for (int off = 128; off > 0; off >>= 1) {
      if (tid < off) { if (red[tid + off] > red[tid]) red[tid] = red[tid + off]; }
      __syncthreads();
    }
    best = red[0];
    for (int i = tid; i < 2048; i += 256) {
      if (pool[i] == best) pool[i] = 0ull;   // unique (contains ~key_idx)
    }
    if (tid == 0) {
      float s = sort2f((unsigned int)(best >> 32));
      int idx = (int)(~(unsigned int)best);
      sel_idx[b * TOPK + r] = idx;
      sel_w[b * TOPK + r] = __expf(s - Mf) / Sf;
    }
    __syncthreads();
  }
}

// ---- K4: gather values rows + write weights ----
__global__ __launch_bounds__(64) void gather_kernel(
    const float* __restrict__ values, const int* __restrict__ sel_idx,
    const float* __restrict__ sel_w, float* __restrict__ out) {
  const int row = blockIdx.x;          // b*32 + j
  const int tid = threadIdx.x;
  const int idx = sel_idx[row];
  const float4* src = (const float4*)(values + (size_t)idx * DD);
  float4* dst = (float4*)(out + (size_t)row * DD);
  dst[tid] = src[tid];
  if (tid == 0) out[(size_t)NB * TOPK * DD + row] = sel_w[row];
}

extern "C" void kernel_launch(void* const* d_in, const int* in_sizes, int n_in,
                              void* d_out, int out_size, void* d_ws, size_t ws_size,
                              hipStream_t stream) {
  (void)in_sizes; (void)n_in; (void)out_size; (void)ws_size;
  const float* query  = (const float*)d_in[0];
  const float* keys   = (const float*)d_in[1];
  const float* values = (const float*)d_in[2];
  const float* Wq     = (const float*)d_in[3];
  const float* bq     = (const float*)d_in[4];
  float* out = (float*)d_out;

  // workspace carve-up (all 256B aligned); total ~17.9 MB
  char* ws = (char*)d_ws;
  size_t off = 0;
  float* qs = (float*)(ws + off);                    off += (size_t)NB * DD * 4;          // 64 KB
  float* maxes = (float*)(ws + off);                 off += (size_t)NW * NB * 4;          // 512 KB
  float* sums = (float*)(ws + off);                  off += (size_t)NW * NB * 4;          // 512 KB
  unsigned long long* cands =
      (unsigned long long*)(ws + off);               off += (size_t)NW * NB * CPW * 8;    // 16 MB
  int* sel_idx = (int*)(ws + off);                   off += (size_t)NB * TOPK * 4;
  float* sel_w = (float*)(ws + off);                 off += (size_t)NB * TOPK * 4;

  hipLaunchKernelGGL(qproj_kernel, dim3(NB), dim3(256), 0, stream, query, Wq, bq, qs);
  hipLaunchKernelGGL(score_topk_kernel, dim3(NW), dim3(64), 0, stream,
                     keys, qs, maxes, sums, cands);
  hipLaunchKernelGGL(merge_kernel, dim3(NB), dim3(256), 0, stream,
                     maxes, sums, cands, sel_idx, sel_w);
  hipLaunchKernelGGL(gather_kernel, dim3(NB * TOPK), dim3(64), 0, stream,
                     values, sel_idx, sel_w, out);
}